// Round 1
// baseline (318.237 us; speedup 1.0000x reference)
//
#include <hip/hip_runtime.h>

// MACE symmetric contraction (corr-3), N=2048, NL=16, C=128, E=10, P3=23, P2=4, P1=1.
// out[n,c] = sum_{a<=b<=i} A3[t,tri,c] x_a x_b x_i + sum_{a<=b} A2[t,pr,c] x_a x_b
//          + sum_a A1[t,a,c] x_a,  with A3 = U3sym @ W3[t] etc. (t = atom type).
// R3: Horner factorization of the triangular nest:
//       out = sum_a x_a * ( w1_a + sum_{b>=a} x_b * ( w2_ab + sum_{i>=b} w3_abi * x_i ) )
//     -> 1 FMA per cubic monomial (was mul+fma), linear term folded in free.
//     Plus: bucketing fused to ONE single-block kernel (LDS atomics, was 3 dispatches),
//     and k_buildA batched 4 tris/block with float4 stores (W3 rows amortized 4x).

constexpr int NL = 16;
constexpr int CC = 128;
constexpr int EE = 10;
constexpr int P3 = 23;
constexpr int P2 = 4;
constexpr int P1 = 1;
constexpr int NTRI = 816;   // C(18,3): a<=b<=i from 16
constexpr int NPAIR = 136;  // C(17,2): a<=b from 16
constexpr int GG = 4;       // atoms per group
constexpr int ASPLIT = 4;   // nest split: a in [0,4) | [4,16)

constexpr int pairsBefore(int a) {
    int s = 0;
    for (int x = 0; x < a; x++) s += NL - x;
    return s;
}
constexpr int trisBefore(int a) {
    int s = 0;
    for (int x = 0; x < a; x++) s += (NL - x) * (NL - x + 1) / 2;
    return s;
}
static_assert(trisBefore(ASPLIT) % 4 == 0, "tri split must be float4-aligned");
static_assert(pairsBefore(ASPLIT) % 2 == 0, "pair split must be float2-aligned");

// ---------------- Precompute: symmetrized U tensors ----------------
__global__ void k_symU(const float* __restrict__ U3, const float* __restrict__ U2,
                       float* __restrict__ U3s, float* __restrict__ U2s) {
    int idx = blockIdx.x * blockDim.x + threadIdx.x;
    if (idx < NTRI * P3) {
        int tri = idx / P3, k = idx % P3;
        int rem = tri, a = 0;
        while (rem >= (NL - a) * (NL - a + 1) / 2) { rem -= (NL - a) * (NL - a + 1) / 2; a++; }
        int b = a;
        while (rem >= NL - b) { rem -= NL - b; b++; }
        int i = b + rem;
        auto u = [&](int p, int q, int r) { return U3[((p * NL + q) * NL + r) * P3 + k]; };
        float s = u(a,b,i) + u(a,i,b) + u(b,a,i) + u(b,i,a) + u(i,a,b) + u(i,b,a);
        int m = (a == b && b == i) ? 6 : ((a == b || b == i) ? 2 : 1);
        U3s[idx] = s / (float)m;
    } else if (idx < NTRI * P3 + NPAIR * P2) {
        int j = idx - NTRI * P3;
        int pr = j / P2, k = j % P2;
        int rem = pr, a = 0;
        while (rem >= NL - a) { rem -= NL - a; a++; }
        int b = a + rem;
        float s = U2[(a * NL + b) * P2 + k];
        if (a != b) s += U2[(b * NL + a) * P2 + k];
        U2s[pr * P2 + k] = s;
    }
}

// ---------------- Precompute: per-type coefficient tables (interleaved) -------
// A3 layout: [t][tri/4][c][4]  -> thread c reads float4 of 4 consecutive tri
// A2 layout: [t][pr/2][c][2]   -> float2 of 2 consecutive pairs
// A1 layout: [t][a][c]         -> scalar
// One block = 4 tris (float4 store) or 2 pairs (float2 store) or one type's A1.
__global__ void k_buildA(const float* __restrict__ U3s, const float* __restrict__ U2s,
                         const float* __restrict__ U1,
                         const float* __restrict__ W3, const float* __restrict__ W2,
                         const float* __restrict__ W1,
                         float* __restrict__ A3, float* __restrict__ A2, float* __restrict__ A1) {
    constexpr int NB3 = EE * (NTRI / 4);
    constexpr int NB2 = EE * (NPAIR / 2);
    int b = blockIdx.x;
    int c = threadIdx.x;  // 128 threads = channels
    if (b < NB3) {
        int t = b / (NTRI / 4), tri4 = b % (NTRI / 4);
        float4 sv = {0.f, 0.f, 0.f, 0.f};
        #pragma unroll
        for (int k = 0; k < P3; k++) {
            float w = W3[(t * P3 + k) * CC + c];
            sv.x += U3s[(tri4 * 4 + 0) * P3 + k] * w;
            sv.y += U3s[(tri4 * 4 + 1) * P3 + k] * w;
            sv.z += U3s[(tri4 * 4 + 2) * P3 + k] * w;
            sv.w += U3s[(tri4 * 4 + 3) * P3 + k] * w;
        }
        ((float4*)A3)[((size_t)t * (NTRI / 4) + tri4) * CC + c] = sv;
    } else if (b < NB3 + NB2) {
        int j = b - NB3;
        int t = j / (NPAIR / 2), pr2 = j % (NPAIR / 2);
        float2 sv = {0.f, 0.f};
        #pragma unroll
        for (int k = 0; k < P2; k++) {
            float w = W2[(t * P2 + k) * CC + c];
            sv.x += U2s[(pr2 * 2 + 0) * P2 + k] * w;
            sv.y += U2s[(pr2 * 2 + 1) * P2 + k] * w;
        }
        ((float2*)A2)[((size_t)t * (NPAIR / 2) + pr2) * CC + c] = sv;
    } else {
        int t = b - NB3 - NB2;
        #pragma unroll
        for (int a = 0; a < NL; a++) {
            float s = 0.f;
            #pragma unroll
            for (int k = 0; k < P1; k++) s += U1[a * P1 + k] * W1[(t * P1 + k) * CC + c];
            A1[((size_t)t * NL + a) * CC + c] = s;
        }
    }
}

// ---------------- Atom bucketing by type: ONE single-block kernel ----------
__global__ void k_prep(const int* __restrict__ types, int* __restrict__ buckets,
                       int* __restrict__ groups, int* __restrict__ ngroups, int N) {
    __shared__ int scnt[EE];
    __shared__ int goff[EE + 1];
    int tid = threadIdx.x;
    if (tid < EE) scnt[tid] = 0;
    __syncthreads();
    for (int n = tid; n < N; n += blockDim.x) {
        int t = types[n];
        int pos = atomicAdd(&scnt[t], 1);
        buckets[t * N + pos] = n;
    }
    __syncthreads();
    if (tid == 0) {
        int off = 0;
        for (int t = 0; t < EE; t++) { goff[t] = off; off += (scnt[t] + GG - 1) / GG; }
        goff[EE] = off;
        *ngroups = off;
    }
    __syncthreads();
    for (int t = 0; t < EE; t++) {
        int cnt = scnt[t];
        int ng = (cnt + GG - 1) / GG;
        for (int g = tid; g < ng; g += blockDim.x) {
            int* gr = &groups[(goff[t] + g) * 8];
            int nv = cnt - g * GG; if (nv > GG) nv = GG;
            gr[0] = t;
            gr[5] = nv;
            for (int j = 0; j < GG; j++) {
                int jj = j < nv ? j : nv - 1;
                gr[1 + j] = buckets[t * N + g * GG + jj];
            }
        }
    }
}

// ---------------- Main: Horner-factored cubic form per (group-half, channel) --
// out = sum_a x_a * ( w1_a + sum_{b>=a} x_b * ( w2_ab + sum_{i>=b} w3_abi x_i ) )
// One FMA per cubic monomial; tri/pr indices are compile-time constants after
// full unroll, so all w-extractions and load offsets are static.
template <int A0, int A1e>
__device__ __forceinline__ void eval_nest(const float (&xv)[GG][NL],
                                          const float4* __restrict__ a3v,
                                          const float2* __restrict__ a2v,
                                          const float* __restrict__ a1p,
                                          float (&acc)[GG]) {
    float4 w4 = {0.f, 0.f, 0.f, 0.f};
    float2 wp = {0.f, 0.f};
    int tri = trisBefore(A0), pr = pairsBefore(A0);
    #pragma unroll
    for (int a = A0; a < A1e; a++) {
        float w1 = a1p[a * CC];
        float q[GG];
        #pragma unroll
        for (int g = 0; g < GG; g++) q[g] = w1;
        #pragma unroll
        for (int b = a; b < NL; b++) {
            // first i == b (always exists): init s with a mul, not 0+fma
            if ((tri & 3) == 0) w4 = a3v[(size_t)(tri >> 2) * CC];
            {
                int r = tri & 3;
                float w3 = (r == 0) ? w4.x : (r == 1) ? w4.y : (r == 2) ? w4.z : w4.w;
                tri++;
                float s[GG];
                #pragma unroll
                for (int g = 0; g < GG; g++) s[g] = w3 * xv[g][b];
                #pragma unroll
                for (int i = b + 1; i < NL; i++) {
                    if ((tri & 3) == 0) w4 = a3v[(size_t)(tri >> 2) * CC];
                    int ri = tri & 3;
                    float w3i = (ri == 0) ? w4.x : (ri == 1) ? w4.y : (ri == 2) ? w4.z : w4.w;
                    tri++;
                    #pragma unroll
                    for (int g = 0; g < GG; g++) s[g] += w3i * xv[g][i];
                }
                if ((pr & 1) == 0) wp = a2v[(size_t)(pr >> 1) * CC];
                float w2 = ((pr & 1) == 0) ? wp.x : wp.y;
                pr++;
                #pragma unroll
                for (int g = 0; g < GG; g++) q[g] += xv[g][b] * (w2 + s[g]);
            }
        }
        #pragma unroll
        for (int g = 0; g < GG; g++) acc[g] += xv[g][a] * q[g];
    }
}

__global__ __launch_bounds__(CC, 3) void k_main(const float* __restrict__ x,
                                                const float* __restrict__ A3,
                                                const float* __restrict__ A2,
                                                const float* __restrict__ A1,
                                                const int* __restrict__ groups,
                                                const int* __restrict__ ngroups,
                                                float* __restrict__ out) {
    int blk = blockIdx.x;
    if (blk >= *ngroups) return;
    const int* gr = groups + blk * 8;
    int t = gr[0];
    int nvalid = gr[5];
    int c = threadIdx.x;

    int na[GG];
    #pragma unroll
    for (int g = 0; g < GG; g++) na[g] = gr[1 + g];

    float xv[GG][NL];
    #pragma unroll
    for (int g = 0; g < GG; g++)
        #pragma unroll
        for (int i = 0; i < NL; i++)
            xv[g][i] = x[((size_t)na[g] * NL + i) * CC + c];

    const float4* a3v = (const float4*)A3 + (size_t)t * (NTRI / 4) * CC + c;
    const float2* a2v = (const float2*)A2 + (size_t)t * (NPAIR / 2) * CC + c;
    const float* a1p = A1 + (size_t)t * NL * CC + c;

    float acc[GG] = {0.f, 0.f, 0.f, 0.f};
    if (blockIdx.y == 0)
        eval_nest<0, ASPLIT>(xv, a3v, a2v, a1p, acc);
    else
        eval_nest<ASPLIT, NL>(xv, a3v, a2v, a1p, acc);

    #pragma unroll
    for (int g = 0; g < GG; g++)
        if (g < nvalid) atomicAdd(&out[(size_t)na[g] * CC + c], acc[g]);
}

extern "C" void kernel_launch(void* const* d_in, const int* in_sizes, int n_in,
                              void* d_out, int out_size, void* d_ws, size_t ws_size,
                              hipStream_t stream) {
    const float* x   = (const float*)d_in[0];
    const int* types = (const int*)d_in[1];
    const float* U3  = (const float*)d_in[2];
    const float* U2  = (const float*)d_in[3];
    const float* U1  = (const float*)d_in[4];
    const float* W3  = (const float*)d_in[5];
    const float* W2  = (const float*)d_in[6];
    const float* W1  = (const float*)d_in[7];
    float* out = (float*)d_out;
    int N = in_sizes[1];  // atom count (2048)

    int ngmax = (N + GG - 1) / GG + EE;  // strict upper bound on group count

    float* ws   = (float*)d_ws;
    float* U3s  = ws;                           // NTRI*P3
    float* U2s  = U3s + NTRI * P3;              // NPAIR*P2
    float* A3   = U2s + NPAIR * P2;             // EE*NTRI*CC (interleaved x4)
    float* A2   = A3 + (size_t)EE * NTRI * CC;  // EE*NPAIR*CC (interleaved x2)
    float* A1   = A2 + (size_t)EE * NPAIR * CC; // EE*NL*CC
    int* buckets = (int*)(A1 + (size_t)EE * NL * CC);  // EE*N
    int* groups  = buckets + (size_t)EE * N;    // ngmax*8
    int* ngroups = groups + (size_t)ngmax * 8;

    hipMemsetAsync(out, 0, (size_t)out_size * sizeof(float), stream);

    int symThreads = NTRI * P3 + NPAIR * P2;
    hipLaunchKernelGGL(k_symU, dim3((symThreads + 255) / 256), dim3(256), 0, stream,
                       U3, U2, U3s, U2s);
    hipLaunchKernelGGL(k_buildA, dim3(EE * (NTRI / 4) + EE * (NPAIR / 2) + EE), dim3(CC), 0,
                       stream, U3s, U2s, U1, W3, W2, W1, A3, A2, A1);
    hipLaunchKernelGGL(k_prep, dim3(1), dim3(256), 0, stream,
                       types, buckets, groups, ngroups, N);
    hipLaunchKernelGGL(k_main, dim3(ngmax, 2), dim3(CC), 0, stream,
                       x, A3, A2, A1, groups, ngroups, out);
}

// Round 2
// 275.504 us; speedup vs baseline: 1.1551x; 1.1551x over previous
//
#include <hip/hip_runtime.h>

// MACE symmetric contraction (corr-3), N=2048, NL=16, C=128, E=10, P3=23, P2=4, P1=1.
// out[n,c] = sum_{a<=b<=i} A3[t,tri,c] x_a x_b x_i + sum_{a<=b} A2[t,pr,c] x_a x_b
//          + sum_a A1[t,a,c] x_a,  with A3 = U3sym @ W3[t] etc. (t = atom type).
// R4: back to the R2-proven loop skeleton (R3's Horner restructure triggered a
// scratch storm: 253MB/dispatch scratch writes, VALUBusy 4%). Inside the proven
// skeleton, use a per-pair running sum s[g] += w3*x_i (1 FMA/cubic monomial,
// epilogue acc += p*(w2+s)). Plus: XCD-chunked bijective block swizzle so each
// XCD's L2 holds its types' A3 slice (groups are type-sorted), and a 3-way
// a-split {0,4,8,16} for ~6 blocks/CU.

constexpr int NL = 16;
constexpr int CC = 128;
constexpr int EE = 10;
constexpr int P3 = 23;
constexpr int P2 = 4;
constexpr int P1 = 1;
constexpr int NTRI = 816;   // C(18,3): a<=b<=i from 16
constexpr int NPAIR = 136;  // C(17,2): a<=b from 16
constexpr int GG = 4;       // atoms per group
constexpr int S1 = 4;       // nest split: a in [0,4) | [4,8) | [8,16)
constexpr int S2 = 8;

constexpr int pairsBefore(int a) {
    int s = 0;
    for (int x = 0; x < a; x++) s += NL - x;
    return s;
}
constexpr int trisBefore(int a) {
    int s = 0;
    for (int x = 0; x < a; x++) s += (NL - x) * (NL - x + 1) / 2;
    return s;
}
static_assert(trisBefore(S1) % 4 == 0, "tri split1 must be float4-aligned");
static_assert(pairsBefore(S1) % 2 == 0, "pair split1 must be float2-aligned");
static_assert(trisBefore(S2) % 4 == 0, "tri split2 must be float4-aligned");
static_assert(pairsBefore(S2) % 2 == 0, "pair split2 must be float2-aligned");

// ---------------- Precompute: symmetrized U tensors ----------------
__global__ void k_symU(const float* __restrict__ U3, const float* __restrict__ U2,
                       float* __restrict__ U3s, float* __restrict__ U2s) {
    int idx = blockIdx.x * blockDim.x + threadIdx.x;
    if (idx < NTRI * P3) {
        int tri = idx / P3, k = idx % P3;
        int rem = tri, a = 0;
        while (rem >= (NL - a) * (NL - a + 1) / 2) { rem -= (NL - a) * (NL - a + 1) / 2; a++; }
        int b = a;
        while (rem >= NL - b) { rem -= NL - b; b++; }
        int i = b + rem;
        auto u = [&](int p, int q, int r) { return U3[((p * NL + q) * NL + r) * P3 + k]; };
        float s = u(a,b,i) + u(a,i,b) + u(b,a,i) + u(b,i,a) + u(i,a,b) + u(i,b,a);
        int m = (a == b && b == i) ? 6 : ((a == b || b == i) ? 2 : 1);
        U3s[idx] = s / (float)m;
    } else if (idx < NTRI * P3 + NPAIR * P2) {
        int j = idx - NTRI * P3;
        int pr = j / P2, k = j % P2;
        int rem = pr, a = 0;
        while (rem >= NL - a) { rem -= NL - a; a++; }
        int b = a + rem;
        float s = U2[(a * NL + b) * P2 + k];
        if (a != b) s += U2[(b * NL + a) * P2 + k];
        U2s[pr * P2 + k] = s;
    }
}

// ---------------- Precompute: per-type coefficient tables (interleaved) -------
// A3 layout: [t][tri/4][c][4]  -> thread c reads float4 of 4 consecutive tri
// A2 layout: [t][pr/2][c][2]   -> float2 of 2 consecutive pairs
// A1 layout: [t][a][c]         -> scalar
// One block = 4 tris (float4 store) or 2 pairs (float2 store) or one type's A1.
__global__ void k_buildA(const float* __restrict__ U3s, const float* __restrict__ U2s,
                         const float* __restrict__ U1,
                         const float* __restrict__ W3, const float* __restrict__ W2,
                         const float* __restrict__ W1,
                         float* __restrict__ A3, float* __restrict__ A2, float* __restrict__ A1) {
    constexpr int NB3 = EE * (NTRI / 4);
    constexpr int NB2 = EE * (NPAIR / 2);
    int b = blockIdx.x;
    int c = threadIdx.x;  // 128 threads = channels
    if (b < NB3) {
        int t = b / (NTRI / 4), tri4 = b % (NTRI / 4);
        float4 sv = {0.f, 0.f, 0.f, 0.f};
        #pragma unroll
        for (int k = 0; k < P3; k++) {
            float w = W3[(t * P3 + k) * CC + c];
            sv.x += U3s[(tri4 * 4 + 0) * P3 + k] * w;
            sv.y += U3s[(tri4 * 4 + 1) * P3 + k] * w;
            sv.z += U3s[(tri4 * 4 + 2) * P3 + k] * w;
            sv.w += U3s[(tri4 * 4 + 3) * P3 + k] * w;
        }
        ((float4*)A3)[((size_t)t * (NTRI / 4) + tri4) * CC + c] = sv;
    } else if (b < NB3 + NB2) {
        int j = b - NB3;
        int t = j / (NPAIR / 2), pr2 = j % (NPAIR / 2);
        float2 sv = {0.f, 0.f};
        #pragma unroll
        for (int k = 0; k < P2; k++) {
            float w = W2[(t * P2 + k) * CC + c];
            sv.x += U2s[(pr2 * 2 + 0) * P2 + k] * w;
            sv.y += U2s[(pr2 * 2 + 1) * P2 + k] * w;
        }
        ((float2*)A2)[((size_t)t * (NPAIR / 2) + pr2) * CC + c] = sv;
    } else {
        int t = b - NB3 - NB2;
        #pragma unroll
        for (int a = 0; a < NL; a++) {
            float s = 0.f;
            #pragma unroll
            for (int k = 0; k < P1; k++) s += U1[a * P1 + k] * W1[(t * P1 + k) * CC + c];
            A1[((size_t)t * NL + a) * CC + c] = s;
        }
    }
}

// ---------------- Atom bucketing by type: ONE single-block kernel ----------
__global__ void k_prep(const int* __restrict__ types, int* __restrict__ buckets,
                       int* __restrict__ groups, int* __restrict__ ngroups, int N) {
    __shared__ int scnt[EE];
    __shared__ int goff[EE + 1];
    int tid = threadIdx.x;
    if (tid < EE) scnt[tid] = 0;
    __syncthreads();
    for (int n = tid; n < N; n += blockDim.x) {
        int t = types[n];
        int pos = atomicAdd(&scnt[t], 1);
        buckets[t * N + pos] = n;
    }
    __syncthreads();
    if (tid == 0) {
        int off = 0;
        for (int t = 0; t < EE; t++) { goff[t] = off; off += (scnt[t] + GG - 1) / GG; }
        goff[EE] = off;
        *ngroups = off;
    }
    __syncthreads();
    for (int t = 0; t < EE; t++) {
        int cnt = scnt[t];
        int ng = (cnt + GG - 1) / GG;
        for (int g = tid; g < ng; g += blockDim.x) {
            int* gr = &groups[(goff[t] + g) * 8];
            int nv = cnt - g * GG; if (nv > GG) nv = GG;
            gr[0] = t;
            gr[5] = nv;
            for (int j = 0; j < GG; j++) {
                int jj = j < nv ? j : nv - 1;
                gr[1 + j] = buckets[t * N + g * GG + jj];
            }
        }
    }
}

// ---------------- Main: cubic form per (group-slice, channel) ----------------
// R2-proven skeleton. Per (a,b): p = x_a*x_b; s accumulates sum_i w3*x_i over
// i in [b,NL); epilogue acc += p*(w2+s). One FMA per cubic monomial.
template <int A0, int A1e, bool LIN>
__device__ __forceinline__ void eval_nest(const float (&xv)[GG][NL],
                                          const float4* __restrict__ a3v,
                                          const float2* __restrict__ a2v,
                                          const float* __restrict__ a1p,
                                          float (&acc)[GG]) {
    if (LIN) {
        #pragma unroll
        for (int a = 0; a < NL; a++) {
            float w = a1p[a * CC];
            #pragma unroll
            for (int g = 0; g < GG; g++) acc[g] += w * xv[g][a];
        }
    }
    float4 w4 = {0.f, 0.f, 0.f, 0.f};
    float2 wp = {0.f, 0.f};
    int tri = trisBefore(A0), pr = pairsBefore(A0);
    #pragma unroll
    for (int a = A0; a < A1e; a++) {
        #pragma unroll
        for (int b = a; b < NL; b++) {
            float p[GG], s[GG];
            #pragma unroll
            for (int g = 0; g < GG; g++) p[g] = xv[g][a] * xv[g][b];
            #pragma unroll
            for (int i = b; i < NL; i++) {
                if ((tri & 3) == 0) w4 = a3v[(size_t)(tri >> 2) * CC];
                int r = tri & 3;
                float w3 = (r == 0) ? w4.x : (r == 1) ? w4.y : (r == 2) ? w4.z : w4.w;
                tri++;
                if (i == b) {
                    #pragma unroll
                    for (int g = 0; g < GG; g++) s[g] = w3 * xv[g][b];
                } else {
                    #pragma unroll
                    for (int g = 0; g < GG; g++) s[g] += w3 * xv[g][i];
                }
            }
            if ((pr & 1) == 0) wp = a2v[(size_t)(pr >> 1) * CC];
            float w2 = ((pr & 1) == 0) ? wp.x : wp.y;
            pr++;
            #pragma unroll
            for (int g = 0; g < GG; g++) acc[g] += p[g] * (w2 + s[g]);
        }
    }
}

__global__ __launch_bounds__(CC, 3) void k_main(const float* __restrict__ x,
                                                const float* __restrict__ A3,
                                                const float* __restrict__ A2,
                                                const float* __restrict__ A1,
                                                const int* __restrict__ groups,
                                                const int* __restrict__ ngroups,
                                                float* __restrict__ out) {
    // XCD-chunked bijective swizzle (m204 form): physical blocks round-robin
    // XCDs; give each XCD a contiguous LOGICAL group chunk so its L2 holds the
    // A3 slices of only ~1-2 atom types (groups are type-sorted).
    int pb = blockIdx.x;
    int nb = gridDim.x;
    int q = nb >> 3, r = nb & 7;
    int xcd = pb & 7, sub = pb >> 3;
    int blk = (xcd < r ? xcd * (q + 1) : r * (q + 1) + (xcd - r) * q) + sub;
    if (blk >= *ngroups) return;
    const int* gr = groups + blk * 8;
    int t = gr[0];
    int nvalid = gr[5];
    int c = threadIdx.x;

    int na[GG];
    #pragma unroll
    for (int g = 0; g < GG; g++) na[g] = gr[1 + g];

    float xv[GG][NL];
    #pragma unroll
    for (int g = 0; g < GG; g++)
        #pragma unroll
        for (int i = 0; i < NL; i++)
            xv[g][i] = x[((size_t)na[g] * NL + i) * CC + c];

    const float4* a3v = (const float4*)A3 + (size_t)t * (NTRI / 4) * CC + c;
    const float2* a2v = (const float2*)A2 + (size_t)t * (NPAIR / 2) * CC + c;
    const float* a1p = A1 + (size_t)t * NL * CC + c;

    float acc[GG] = {0.f, 0.f, 0.f, 0.f};
    if (blockIdx.y == 0)
        eval_nest<0, S1, true>(xv, a3v, a2v, a1p, acc);
    else if (blockIdx.y == 1)
        eval_nest<S1, S2, false>(xv, a3v, a2v, a1p, acc);
    else
        eval_nest<S2, NL, false>(xv, a3v, a2v, a1p, acc);

    #pragma unroll
    for (int g = 0; g < GG; g++)
        if (g < nvalid) atomicAdd(&out[(size_t)na[g] * CC + c], acc[g]);
}

extern "C" void kernel_launch(void* const* d_in, const int* in_sizes, int n_in,
                              void* d_out, int out_size, void* d_ws, size_t ws_size,
                              hipStream_t stream) {
    const float* x   = (const float*)d_in[0];
    const int* types = (const int*)d_in[1];
    const float* U3  = (const float*)d_in[2];
    const float* U2  = (const float*)d_in[3];
    const float* U1  = (const float*)d_in[4];
    const float* W3  = (const float*)d_in[5];
    const float* W2  = (const float*)d_in[6];
    const float* W1  = (const float*)d_in[7];
    float* out = (float*)d_out;
    int N = in_sizes[1];  // atom count (2048)

    int ngmax = (N + GG - 1) / GG + EE;  // strict upper bound on group count

    float* ws   = (float*)d_ws;
    float* U3s  = ws;                           // NTRI*P3
    float* U2s  = U3s + NTRI * P3;              // NPAIR*P2
    float* A3   = U2s + NPAIR * P2;             // EE*NTRI*CC (interleaved x4)
    float* A2   = A3 + (size_t)EE * NTRI * CC;  // EE*NPAIR*CC (interleaved x2)
    float* A1   = A2 + (size_t)EE * NPAIR * CC; // EE*NL*CC
    int* buckets = (int*)(A1 + (size_t)EE * NL * CC);  // EE*N
    int* groups  = buckets + (size_t)EE * N;    // ngmax*8
    int* ngroups = groups + (size_t)ngmax * 8;

    hipMemsetAsync(out, 0, (size_t)out_size * sizeof(float), stream);

    int symThreads = NTRI * P3 + NPAIR * P2;
    hipLaunchKernelGGL(k_symU, dim3((symThreads + 255) / 256), dim3(256), 0, stream,
                       U3, U2, U3s, U2s);
    hipLaunchKernelGGL(k_buildA, dim3(EE * (NTRI / 4) + EE * (NPAIR / 2) + EE), dim3(CC), 0,
                       stream, U3s, U2s, U1, W3, W2, W1, A3, A2, A1);
    hipLaunchKernelGGL(k_prep, dim3(1), dim3(256), 0, stream,
                       types, buckets, groups, ngroups, N);
    hipLaunchKernelGGL(k_main, dim3(ngmax, 3), dim3(CC), 0, stream,
                       x, A3, A2, A1, groups, ngroups, out);
}

// Round 3
// 231.653 us; speedup vs baseline: 1.3738x; 1.1893x over previous
//
#include <hip/hip_runtime.h>

// MACE symmetric contraction (corr-3), N=2048, NL=16, C=128, E=10, P3=23, P2=4, P1=1.
// out[n,c] = sum_{a<=b<=i} A3[t,tri,c] x_a x_b x_i + sum_{a<=b} A2[t,pr,c] x_a x_b
//          + sum_a A1[t,a,c] x_a,  with A3 = U3sym @ W3[t] etc. (t = atom type).
// R5: ONE change vs R4 — __launch_bounds__(128, 2) instead of (128, 3).
// R3/R4 rocprof showed VGPR_Count=84 (= 512/6: the (128,3) bound made the
// compiler cap the register file for ~6 waves/SIMD) while the kernel's live set
// (xv[4][16]=64 regs + s/p/acc/w4 + addrs ~= 100) needs ~100+ -> ~20-40 spilled
// floats re-read inside the fully-unrolled 450-tri nest = 186MB scratch writes,
// VALUBusy 5%, latency-bound. Relaxing the cap keeps the whole state resident.

constexpr int NL = 16;
constexpr int CC = 128;
constexpr int EE = 10;
constexpr int P3 = 23;
constexpr int P2 = 4;
constexpr int P1 = 1;
constexpr int NTRI = 816;   // C(18,3): a<=b<=i from 16
constexpr int NPAIR = 136;  // C(17,2): a<=b from 16
constexpr int GG = 4;       // atoms per group
constexpr int S1 = 4;       // nest split: a in [0,4) | [4,8) | [8,16)
constexpr int S2 = 8;

constexpr int pairsBefore(int a) {
    int s = 0;
    for (int x = 0; x < a; x++) s += NL - x;
    return s;
}
constexpr int trisBefore(int a) {
    int s = 0;
    for (int x = 0; x < a; x++) s += (NL - x) * (NL - x + 1) / 2;
    return s;
}
static_assert(trisBefore(S1) % 4 == 0, "tri split1 must be float4-aligned");
static_assert(pairsBefore(S1) % 2 == 0, "pair split1 must be float2-aligned");
static_assert(trisBefore(S2) % 4 == 0, "tri split2 must be float4-aligned");
static_assert(pairsBefore(S2) % 2 == 0, "pair split2 must be float2-aligned");

// ---------------- Precompute: symmetrized U tensors ----------------
__global__ void k_symU(const float* __restrict__ U3, const float* __restrict__ U2,
                       float* __restrict__ U3s, float* __restrict__ U2s) {
    int idx = blockIdx.x * blockDim.x + threadIdx.x;
    if (idx < NTRI * P3) {
        int tri = idx / P3, k = idx % P3;
        int rem = tri, a = 0;
        while (rem >= (NL - a) * (NL - a + 1) / 2) { rem -= (NL - a) * (NL - a + 1) / 2; a++; }
        int b = a;
        while (rem >= NL - b) { rem -= NL - b; b++; }
        int i = b + rem;
        auto u = [&](int p, int q, int r) { return U3[((p * NL + q) * NL + r) * P3 + k]; };
        float s = u(a,b,i) + u(a,i,b) + u(b,a,i) + u(b,i,a) + u(i,a,b) + u(i,b,a);
        int m = (a == b && b == i) ? 6 : ((a == b || b == i) ? 2 : 1);
        U3s[idx] = s / (float)m;
    } else if (idx < NTRI * P3 + NPAIR * P2) {
        int j = idx - NTRI * P3;
        int pr = j / P2, k = j % P2;
        int rem = pr, a = 0;
        while (rem >= NL - a) { rem -= NL - a; a++; }
        int b = a + rem;
        float s = U2[(a * NL + b) * P2 + k];
        if (a != b) s += U2[(b * NL + a) * P2 + k];
        U2s[pr * P2 + k] = s;
    }
}

// ---------------- Precompute: per-type coefficient tables (interleaved) -------
// A3 layout: [t][tri/4][c][4]  -> thread c reads float4 of 4 consecutive tri
// A2 layout: [t][pr/2][c][2]   -> float2 of 2 consecutive pairs
// A1 layout: [t][a][c]         -> scalar
// One block = 4 tris (float4 store) or 2 pairs (float2 store) or one type's A1.
__global__ void k_buildA(const float* __restrict__ U3s, const float* __restrict__ U2s,
                         const float* __restrict__ U1,
                         const float* __restrict__ W3, const float* __restrict__ W2,
                         const float* __restrict__ W1,
                         float* __restrict__ A3, float* __restrict__ A2, float* __restrict__ A1) {
    constexpr int NB3 = EE * (NTRI / 4);
    constexpr int NB2 = EE * (NPAIR / 2);
    int b = blockIdx.x;
    int c = threadIdx.x;  // 128 threads = channels
    if (b < NB3) {
        int t = b / (NTRI / 4), tri4 = b % (NTRI / 4);
        float4 sv = {0.f, 0.f, 0.f, 0.f};
        #pragma unroll
        for (int k = 0; k < P3; k++) {
            float w = W3[(t * P3 + k) * CC + c];
            sv.x += U3s[(tri4 * 4 + 0) * P3 + k] * w;
            sv.y += U3s[(tri4 * 4 + 1) * P3 + k] * w;
            sv.z += U3s[(tri4 * 4 + 2) * P3 + k] * w;
            sv.w += U3s[(tri4 * 4 + 3) * P3 + k] * w;
        }
        ((float4*)A3)[((size_t)t * (NTRI / 4) + tri4) * CC + c] = sv;
    } else if (b < NB3 + NB2) {
        int j = b - NB3;
        int t = j / (NPAIR / 2), pr2 = j % (NPAIR / 2);
        float2 sv = {0.f, 0.f};
        #pragma unroll
        for (int k = 0; k < P2; k++) {
            float w = W2[(t * P2 + k) * CC + c];
            sv.x += U2s[(pr2 * 2 + 0) * P2 + k] * w;
            sv.y += U2s[(pr2 * 2 + 1) * P2 + k] * w;
        }
        ((float2*)A2)[((size_t)t * (NPAIR / 2) + pr2) * CC + c] = sv;
    } else {
        int t = b - NB3 - NB2;
        #pragma unroll
        for (int a = 0; a < NL; a++) {
            float s = 0.f;
            #pragma unroll
            for (int k = 0; k < P1; k++) s += U1[a * P1 + k] * W1[(t * P1 + k) * CC + c];
            A1[((size_t)t * NL + a) * CC + c] = s;
        }
    }
}

// ---------------- Atom bucketing by type: ONE single-block kernel ----------
__global__ void k_prep(const int* __restrict__ types, int* __restrict__ buckets,
                       int* __restrict__ groups, int* __restrict__ ngroups, int N) {
    __shared__ int scnt[EE];
    __shared__ int goff[EE + 1];
    int tid = threadIdx.x;
    if (tid < EE) scnt[tid] = 0;
    __syncthreads();
    for (int n = tid; n < N; n += blockDim.x) {
        int t = types[n];
        int pos = atomicAdd(&scnt[t], 1);
        buckets[t * N + pos] = n;
    }
    __syncthreads();
    if (tid == 0) {
        int off = 0;
        for (int t = 0; t < EE; t++) { goff[t] = off; off += (scnt[t] + GG - 1) / GG; }
        goff[EE] = off;
        *ngroups = off;
    }
    __syncthreads();
    for (int t = 0; t < EE; t++) {
        int cnt = scnt[t];
        int ng = (cnt + GG - 1) / GG;
        for (int g = tid; g < ng; g += blockDim.x) {
            int* gr = &groups[(goff[t] + g) * 8];
            int nv = cnt - g * GG; if (nv > GG) nv = GG;
            gr[0] = t;
            gr[5] = nv;
            for (int j = 0; j < GG; j++) {
                int jj = j < nv ? j : nv - 1;
                gr[1 + j] = buckets[t * N + g * GG + jj];
            }
        }
    }
}

// ---------------- Main: cubic form per (group-slice, channel) ----------------
// Per (a,b): p = x_a*x_b; s accumulates sum_i w3*x_i over i in [b,NL);
// epilogue acc += p*(w2+s). One FMA per cubic monomial.
template <int A0, int A1e, bool LIN>
__device__ __forceinline__ void eval_nest(const float (&xv)[GG][NL],
                                          const float4* __restrict__ a3v,
                                          const float2* __restrict__ a2v,
                                          const float* __restrict__ a1p,
                                          float (&acc)[GG]) {
    if (LIN) {
        #pragma unroll
        for (int a = 0; a < NL; a++) {
            float w = a1p[a * CC];
            #pragma unroll
            for (int g = 0; g < GG; g++) acc[g] += w * xv[g][a];
        }
    }
    float4 w4 = {0.f, 0.f, 0.f, 0.f};
    float2 wp = {0.f, 0.f};
    int tri = trisBefore(A0), pr = pairsBefore(A0);
    #pragma unroll
    for (int a = A0; a < A1e; a++) {
        #pragma unroll
        for (int b = a; b < NL; b++) {
            float p[GG], s[GG];
            #pragma unroll
            for (int g = 0; g < GG; g++) p[g] = xv[g][a] * xv[g][b];
            #pragma unroll
            for (int i = b; i < NL; i++) {
                if ((tri & 3) == 0) w4 = a3v[(size_t)(tri >> 2) * CC];
                int r = tri & 3;
                float w3 = (r == 0) ? w4.x : (r == 1) ? w4.y : (r == 2) ? w4.z : w4.w;
                tri++;
                if (i == b) {
                    #pragma unroll
                    for (int g = 0; g < GG; g++) s[g] = w3 * xv[g][b];
                } else {
                    #pragma unroll
                    for (int g = 0; g < GG; g++) s[g] += w3 * xv[g][i];
                }
            }
            if ((pr & 1) == 0) wp = a2v[(size_t)(pr >> 1) * CC];
            float w2 = ((pr & 1) == 0) ? wp.x : wp.y;
            pr++;
            #pragma unroll
            for (int g = 0; g < GG; g++) acc[g] += p[g] * (w2 + s[g]);
        }
    }
}

// __launch_bounds__(128, 2): R3/R4's (128,3) capped VGPRs at 84 -> spill storm
// (186MB scratch writes/dispatch, VALUBusy 5%). The live set needs ~100 regs;
// (128,2) allows >=128 and keeps xv/s/p/acc resident. Occupancy ~4 waves/SIMD
// is plenty — the nest is FMA-throughput work, not latency hiding work.
__global__ __launch_bounds__(CC, 2) void k_main(const float* __restrict__ x,
                                                const float* __restrict__ A3,
                                                const float* __restrict__ A2,
                                                const float* __restrict__ A1,
                                                const int* __restrict__ groups,
                                                const int* __restrict__ ngroups,
                                                float* __restrict__ out) {
    // XCD-chunked bijective swizzle (m204 form): physical blocks round-robin
    // XCDs; give each XCD a contiguous LOGICAL group chunk so its L2 holds the
    // A3 slices of only ~1-2 atom types (groups are type-sorted).
    int pb = blockIdx.x;
    int nb = gridDim.x;
    int q = nb >> 3, r = nb & 7;
    int xcd = pb & 7, sub = pb >> 3;
    int blk = (xcd < r ? xcd * (q + 1) : r * (q + 1) + (xcd - r) * q) + sub;
    if (blk >= *ngroups) return;
    const int* gr = groups + blk * 8;
    int t = gr[0];
    int nvalid = gr[5];
    int c = threadIdx.x;

    int na[GG];
    #pragma unroll
    for (int g = 0; g < GG; g++) na[g] = gr[1 + g];

    float xv[GG][NL];
    #pragma unroll
    for (int g = 0; g < GG; g++)
        #pragma unroll
        for (int i = 0; i < NL; i++)
            xv[g][i] = x[((size_t)na[g] * NL + i) * CC + c];

    const float4* a3v = (const float4*)A3 + (size_t)t * (NTRI / 4) * CC + c;
    const float2* a2v = (const float2*)A2 + (size_t)t * (NPAIR / 2) * CC + c;
    const float* a1p = A1 + (size_t)t * NL * CC + c;

    float acc[GG] = {0.f, 0.f, 0.f, 0.f};
    if (blockIdx.y == 0)
        eval_nest<0, S1, true>(xv, a3v, a2v, a1p, acc);
    else if (blockIdx.y == 1)
        eval_nest<S1, S2, false>(xv, a3v, a2v, a1p, acc);
    else
        eval_nest<S2, NL, false>(xv, a3v, a2v, a1p, acc);

    #pragma unroll
    for (int g = 0; g < GG; g++)
        if (g < nvalid) atomicAdd(&out[(size_t)na[g] * CC + c], acc[g]);
}

extern "C" void kernel_launch(void* const* d_in, const int* in_sizes, int n_in,
                              void* d_out, int out_size, void* d_ws, size_t ws_size,
                              hipStream_t stream) {
    const float* x   = (const float*)d_in[0];
    const int* types = (const int*)d_in[1];
    const float* U3  = (const float*)d_in[2];
    const float* U2  = (const float*)d_in[3];
    const float* U1  = (const float*)d_in[4];
    const float* W3  = (const float*)d_in[5];
    const float* W2  = (const float*)d_in[6];
    const float* W1  = (const float*)d_in[7];
    float* out = (float*)d_out;
    int N = in_sizes[1];  // atom count (2048)

    int ngmax = (N + GG - 1) / GG + EE;  // strict upper bound on group count

    float* ws   = (float*)d_ws;
    float* U3s  = ws;                           // NTRI*P3
    float* U2s  = U3s + NTRI * P3;              // NPAIR*P2
    float* A3   = U2s + NPAIR * P2;             // EE*NTRI*CC (interleaved x4)
    float* A2   = A3 + (size_t)EE * NTRI * CC;  // EE*NPAIR*CC (interleaved x2)
    float* A1   = A2 + (size_t)EE * NPAIR * CC; // EE*NL*CC
    int* buckets = (int*)(A1 + (size_t)EE * NL * CC);  // EE*N
    int* groups  = buckets + (size_t)EE * N;    // ngmax*8
    int* ngroups = groups + (size_t)ngmax * 8;

    hipMemsetAsync(out, 0, (size_t)out_size * sizeof(float), stream);

    int symThreads = NTRI * P3 + NPAIR * P2;
    hipLaunchKernelGGL(k_symU, dim3((symThreads + 255) / 256), dim3(256), 0, stream,
                       U3, U2, U3s, U2s);
    hipLaunchKernelGGL(k_buildA, dim3(EE * (NTRI / 4) + EE * (NPAIR / 2) + EE), dim3(CC), 0,
                       stream, U3s, U2s, U1, W3, W2, W1, A3, A2, A1);
    hipLaunchKernelGGL(k_prep, dim3(1), dim3(256), 0, stream,
                       types, buckets, groups, ngroups, N);
    hipLaunchKernelGGL(k_main, dim3(ngmax, 3), dim3(CC), 0, stream,
                       x, A3, A2, A1, groups, ngroups, out);
}

// Round 4
// 221.218 us; speedup vs baseline: 1.4386x; 1.0472x over previous
//
#include <hip/hip_runtime.h>

// MACE symmetric contraction (corr-3), N=2048, NL=16, C=128, E=10, P3=23, P2=4, P1=1.
// out[n,c] = sum_{a<=b<=i} A3[t,tri,c] x_a x_b x_i + sum_{a<=b} A2[t,pr,c] x_a x_b
//          + sum_a A1[t,a,c] x_a,  with A3 = U3sym @ W3[t] etc. (t = atom type).
// R6: ONE change vs R5 — __builtin_amdgcn_sched_barrier(0) after every (a,b)
// pair body in eval_nest. R5 showed VGPR=128 (cap 256 NOT binding) with 118MB
// of scratch STORES: the scheduler hoists ~100 a3v float4 loads across the
// fully-unrolled body (400+ VGPR ideal live set) and the allocator spills the
// hoisted values. Pinning the schedule at pair granularity keeps <=2 weight
// loads in flight -> live set ~100 regs -> no spill. Latency is covered by
// 8 waves/SIMD and the 64 independent FMAs inside each pair.

constexpr int NL = 16;
constexpr int CC = 128;
constexpr int EE = 10;
constexpr int P3 = 23;
constexpr int P2 = 4;
constexpr int P1 = 1;
constexpr int NTRI = 816;   // C(18,3): a<=b<=i from 16
constexpr int NPAIR = 136;  // C(17,2): a<=b from 16
constexpr int GG = 4;       // atoms per group
constexpr int S1 = 4;       // nest split: a in [0,4) | [4,8) | [8,16)
constexpr int S2 = 8;

constexpr int pairsBefore(int a) {
    int s = 0;
    for (int x = 0; x < a; x++) s += NL - x;
    return s;
}
constexpr int trisBefore(int a) {
    int s = 0;
    for (int x = 0; x < a; x++) s += (NL - x) * (NL - x + 1) / 2;
    return s;
}
static_assert(trisBefore(S1) % 4 == 0, "tri split1 must be float4-aligned");
static_assert(pairsBefore(S1) % 2 == 0, "pair split1 must be float2-aligned");
static_assert(trisBefore(S2) % 4 == 0, "tri split2 must be float4-aligned");
static_assert(pairsBefore(S2) % 2 == 0, "pair split2 must be float2-aligned");

// ---------------- Precompute: symmetrized U tensors ----------------
__global__ void k_symU(const float* __restrict__ U3, const float* __restrict__ U2,
                       float* __restrict__ U3s, float* __restrict__ U2s) {
    int idx = blockIdx.x * blockDim.x + threadIdx.x;
    if (idx < NTRI * P3) {
        int tri = idx / P3, k = idx % P3;
        int rem = tri, a = 0;
        while (rem >= (NL - a) * (NL - a + 1) / 2) { rem -= (NL - a) * (NL - a + 1) / 2; a++; }
        int b = a;
        while (rem >= NL - b) { rem -= NL - b; b++; }
        int i = b + rem;
        auto u = [&](int p, int q, int r) { return U3[((p * NL + q) * NL + r) * P3 + k]; };
        float s = u(a,b,i) + u(a,i,b) + u(b,a,i) + u(b,i,a) + u(i,a,b) + u(i,b,a);
        int m = (a == b && b == i) ? 6 : ((a == b || b == i) ? 2 : 1);
        U3s[idx] = s / (float)m;
    } else if (idx < NTRI * P3 + NPAIR * P2) {
        int j = idx - NTRI * P3;
        int pr = j / P2, k = j % P2;
        int rem = pr, a = 0;
        while (rem >= NL - a) { rem -= NL - a; a++; }
        int b = a + rem;
        float s = U2[(a * NL + b) * P2 + k];
        if (a != b) s += U2[(b * NL + a) * P2 + k];
        U2s[pr * P2 + k] = s;
    }
}

// ---------------- Precompute: per-type coefficient tables (interleaved) -------
// A3 layout: [t][tri/4][c][4]  -> thread c reads float4 of 4 consecutive tri
// A2 layout: [t][pr/2][c][2]   -> float2 of 2 consecutive pairs
// A1 layout: [t][a][c]         -> scalar
// One block = 4 tris (float4 store) or 2 pairs (float2 store) or one type's A1.
__global__ void k_buildA(const float* __restrict__ U3s, const float* __restrict__ U2s,
                         const float* __restrict__ U1,
                         const float* __restrict__ W3, const float* __restrict__ W2,
                         const float* __restrict__ W1,
                         float* __restrict__ A3, float* __restrict__ A2, float* __restrict__ A1) {
    constexpr int NB3 = EE * (NTRI / 4);
    constexpr int NB2 = EE * (NPAIR / 2);
    int b = blockIdx.x;
    int c = threadIdx.x;  // 128 threads = channels
    if (b < NB3) {
        int t = b / (NTRI / 4), tri4 = b % (NTRI / 4);
        float4 sv = {0.f, 0.f, 0.f, 0.f};
        #pragma unroll
        for (int k = 0; k < P3; k++) {
            float w = W3[(t * P3 + k) * CC + c];
            sv.x += U3s[(tri4 * 4 + 0) * P3 + k] * w;
            sv.y += U3s[(tri4 * 4 + 1) * P3 + k] * w;
            sv.z += U3s[(tri4 * 4 + 2) * P3 + k] * w;
            sv.w += U3s[(tri4 * 4 + 3) * P3 + k] * w;
        }
        ((float4*)A3)[((size_t)t * (NTRI / 4) + tri4) * CC + c] = sv;
    } else if (b < NB3 + NB2) {
        int j = b - NB3;
        int t = j / (NPAIR / 2), pr2 = j % (NPAIR / 2);
        float2 sv = {0.f, 0.f};
        #pragma unroll
        for (int k = 0; k < P2; k++) {
            float w = W2[(t * P2 + k) * CC + c];
            sv.x += U2s[(pr2 * 2 + 0) * P2 + k] * w;
            sv.y += U2s[(pr2 * 2 + 1) * P2 + k] * w;
        }
        ((float2*)A2)[((size_t)t * (NPAIR / 2) + pr2) * CC + c] = sv;
    } else {
        int t = b - NB3 - NB2;
        #pragma unroll
        for (int a = 0; a < NL; a++) {
            float s = 0.f;
            #pragma unroll
            for (int k = 0; k < P1; k++) s += U1[a * P1 + k] * W1[(t * P1 + k) * CC + c];
            A1[((size_t)t * NL + a) * CC + c] = s;
        }
    }
}

// ---------------- Atom bucketing by type: ONE single-block kernel ----------
__global__ void k_prep(const int* __restrict__ types, int* __restrict__ buckets,
                       int* __restrict__ groups, int* __restrict__ ngroups, int N) {
    __shared__ int scnt[EE];
    __shared__ int goff[EE + 1];
    int tid = threadIdx.x;
    if (tid < EE) scnt[tid] = 0;
    __syncthreads();
    for (int n = tid; n < N; n += blockDim.x) {
        int t = types[n];
        int pos = atomicAdd(&scnt[t], 1);
        buckets[t * N + pos] = n;
    }
    __syncthreads();
    if (tid == 0) {
        int off = 0;
        for (int t = 0; t < EE; t++) { goff[t] = off; off += (scnt[t] + GG - 1) / GG; }
        goff[EE] = off;
        *ngroups = off;
    }
    __syncthreads();
    for (int t = 0; t < EE; t++) {
        int cnt = scnt[t];
        int ng = (cnt + GG - 1) / GG;
        for (int g = tid; g < ng; g += blockDim.x) {
            int* gr = &groups[(goff[t] + g) * 8];
            int nv = cnt - g * GG; if (nv > GG) nv = GG;
            gr[0] = t;
            gr[5] = nv;
            for (int j = 0; j < GG; j++) {
                int jj = j < nv ? j : nv - 1;
                gr[1 + j] = buckets[t * N + g * GG + jj];
            }
        }
    }
}

// ---------------- Main: cubic form per (group-slice, channel) ----------------
// Per (a,b): p = x_a*x_b; s accumulates sum_i w3*x_i over i in [b,NL);
// epilogue acc += p*(w2+s). One FMA per cubic monomial. sched_barrier(0) after
// each pair pins load scheduling to pair granularity (anti-spill).
template <int A0, int A1e, bool LIN>
__device__ __forceinline__ void eval_nest(const float (&xv)[GG][NL],
                                          const float4* __restrict__ a3v,
                                          const float2* __restrict__ a2v,
                                          const float* __restrict__ a1p,
                                          float (&acc)[GG]) {
    if (LIN) {
        #pragma unroll
        for (int a = 0; a < NL; a++) {
            float w = a1p[a * CC];
            #pragma unroll
            for (int g = 0; g < GG; g++) acc[g] += w * xv[g][a];
        }
    }
    float4 w4 = {0.f, 0.f, 0.f, 0.f};
    float2 wp = {0.f, 0.f};
    int tri = trisBefore(A0), pr = pairsBefore(A0);
    #pragma unroll
    for (int a = A0; a < A1e; a++) {
        #pragma unroll
        for (int b = a; b < NL; b++) {
            float p[GG], s[GG];
            #pragma unroll
            for (int g = 0; g < GG; g++) p[g] = xv[g][a] * xv[g][b];
            #pragma unroll
            for (int i = b; i < NL; i++) {
                if ((tri & 3) == 0) w4 = a3v[(size_t)(tri >> 2) * CC];
                int r = tri & 3;
                float w3 = (r == 0) ? w4.x : (r == 1) ? w4.y : (r == 2) ? w4.z : w4.w;
                tri++;
                if (i == b) {
                    #pragma unroll
                    for (int g = 0; g < GG; g++) s[g] = w3 * xv[g][b];
                } else {
                    #pragma unroll
                    for (int g = 0; g < GG; g++) s[g] += w3 * xv[g][i];
                }
            }
            if ((pr & 1) == 0) wp = a2v[(size_t)(pr >> 1) * CC];
            float w2 = ((pr & 1) == 0) ? wp.x : wp.y;
            pr++;
            #pragma unroll
            for (int g = 0; g < GG; g++) acc[g] += p[g] * (w2 + s[g]);
            // Anti-spill: forbid hoisting next pairs' a3v loads above this
            // point. Keeps <=2 w4 loads in flight instead of ~100.
            __builtin_amdgcn_sched_barrier(0);
        }
    }
}

__global__ __launch_bounds__(CC, 2) void k_main(const float* __restrict__ x,
                                                const float* __restrict__ A3,
                                                const float* __restrict__ A2,
                                                const float* __restrict__ A1,
                                                const int* __restrict__ groups,
                                                const int* __restrict__ ngroups,
                                                float* __restrict__ out) {
    // XCD-chunked bijective swizzle (m204 form): physical blocks round-robin
    // XCDs; give each XCD a contiguous LOGICAL group chunk so its L2 holds the
    // A3 slices of only ~1-2 atom types (groups are type-sorted).
    int pb = blockIdx.x;
    int nb = gridDim.x;
    int q = nb >> 3, r = nb & 7;
    int xcd = pb & 7, sub = pb >> 3;
    int blk = (xcd < r ? xcd * (q + 1) : r * (q + 1) + (xcd - r) * q) + sub;
    if (blk >= *ngroups) return;
    const int* gr = groups + blk * 8;
    int t = gr[0];
    int nvalid = gr[5];
    int c = threadIdx.x;

    int na[GG];
    #pragma unroll
    for (int g = 0; g < GG; g++) na[g] = gr[1 + g];

    float xv[GG][NL];
    #pragma unroll
    for (int g = 0; g < GG; g++)
        #pragma unroll
        for (int i = 0; i < NL; i++)
            xv[g][i] = x[((size_t)na[g] * NL + i) * CC + c];

    const float4* a3v = (const float4*)A3 + (size_t)t * (NTRI / 4) * CC + c;
    const float2* a2v = (const float2*)A2 + (size_t)t * (NPAIR / 2) * CC + c;
    const float* a1p = A1 + (size_t)t * NL * CC + c;

    float acc[GG] = {0.f, 0.f, 0.f, 0.f};
    if (blockIdx.y == 0)
        eval_nest<0, S1, true>(xv, a3v, a2v, a1p, acc);
    else if (blockIdx.y == 1)
        eval_nest<S1, S2, false>(xv, a3v, a2v, a1p, acc);
    else
        eval_nest<S2, NL, false>(xv, a3v, a2v, a1p, acc);

    #pragma unroll
    for (int g = 0; g < GG; g++)
        if (g < nvalid) atomicAdd(&out[(size_t)na[g] * CC + c], acc[g]);
}

extern "C" void kernel_launch(void* const* d_in, const int* in_sizes, int n_in,
                              void* d_out, int out_size, void* d_ws, size_t ws_size,
                              hipStream_t stream) {
    const float* x   = (const float*)d_in[0];
    const int* types = (const int*)d_in[1];
    const float* U3  = (const float*)d_in[2];
    const float* U2  = (const float*)d_in[3];
    const float* U1  = (const float*)d_in[4];
    const float* W3  = (const float*)d_in[5];
    const float* W2  = (const float*)d_in[6];
    const float* W1  = (const float*)d_in[7];
    float* out = (float*)d_out;
    int N = in_sizes[1];  // atom count (2048)

    int ngmax = (N + GG - 1) / GG + EE;  // strict upper bound on group count

    float* ws   = (float*)d_ws;
    float* U3s  = ws;                           // NTRI*P3
    float* U2s  = U3s + NTRI * P3;              // NPAIR*P2
    float* A3   = U2s + NPAIR * P2;             // EE*NTRI*CC (interleaved x4)
    float* A2   = A3 + (size_t)EE * NTRI * CC;  // EE*NPAIR*CC (interleaved x2)
    float* A1   = A2 + (size_t)EE * NPAIR * CC; // EE*NL*CC
    int* buckets = (int*)(A1 + (size_t)EE * NL * CC);  // EE*N
    int* groups  = buckets + (size_t)EE * N;    // ngmax*8
    int* ngroups = groups + (size_t)ngmax * 8;

    hipMemsetAsync(out, 0, (size_t)out_size * sizeof(float), stream);

    int symThreads = NTRI * P3 + NPAIR * P2;
    hipLaunchKernelGGL(k_symU, dim3((symThreads + 255) / 256), dim3(256), 0, stream,
                       U3, U2, U3s, U2s);
    hipLaunchKernelGGL(k_buildA, dim3(EE * (NTRI / 4) + EE * (NPAIR / 2) + EE), dim3(CC), 0,
                       stream, U3s, U2s, U1, W3, W2, W1, A3, A2, A1);
    hipLaunchKernelGGL(k_prep, dim3(1), dim3(256), 0, stream,
                       types, buckets, groups, ngroups, N);
    hipLaunchKernelGGL(k_main, dim3(ngmax, 3), dim3(CC), 0, stream,
                       x, A3, A2, A1, groups, ngroups, out);
}